// Round 11
// baseline (176.415 us; speedup 1.0000x reference)
//
#include <hip/hip_runtime.h>
#include <hip/hip_bf16.h>
#include <stdint.h>

typedef __bf16 bf16;
typedef __bf16 bf16x8 __attribute__((ext_vector_type(8)));
typedef __bf16 bf16x4 __attribute__((ext_vector_type(4)));
typedef float  f32x4  __attribute__((ext_vector_type(4)));

#define MROWS 131072   // B*H*W rows

__device__ __forceinline__ f32x4 mfma16(bf16x8 a, bf16x8 b, f32x4 c) {
    return __builtin_amdgcn_mfma_f32_16x16x32_bf16(a, b, c, 0, 0, 0);
}
__device__ __forceinline__ f32x4 zero4() {
    f32x4 z; z[0]=0.f; z[1]=0.f; z[2]=0.f; z[3]=0.f; return z;
}
// DPP row_ror within 16-lane rows: VALU-pipe lane rotate-reduce.
template <int CTRL>
__device__ __forceinline__ float rowror(float x) {
    return __int_as_float(
        __builtin_amdgcn_mov_dpp(__float_as_int(x), CTRL, 0xF, 0xF, false));
}
__device__ __forceinline__ float rowmax16(float m) {
    m = fmaxf(m, rowror<0x128>(m));   // ror:8
    m = fmaxf(m, rowror<0x124>(m));   // ror:4
    m = fmaxf(m, rowror<0x122>(m));   // ror:2
    m = fmaxf(m, rowror<0x121>(m));   // ror:1
    return m;
}
__device__ __forceinline__ float rowsum16(float s) {
    s += rowror<0x128>(s);
    s += rowror<0x124>(s);
    s += rowror<0x122>(s);
    s += rowror<0x121>(s);
    return s;
}

// ------- weight transpose fp32 -> bf16, head-padded layout -------------------
// Wt2[branch][seg(q,k,v)][head][col32][k192], col 24..31 = 0 (head dim 24 -> 32).
// Wpt = Wproj^T [192][192].
__global__ void kw_transpose(const float* __restrict__ Wq, const float* __restrict__ Wkv,
                             const float* __restrict__ Wp, bf16* __restrict__ Wt2,
                             bf16* __restrict__ Wpt) {
    int id = blockIdx.x;
    int k = threadIdx.x;  // 192
    if (id < 768) {
        int col = id & 31;
        int hd  = (id >> 5) & 3;
        int seg = (id >> 7) % 3;
        int br  = id / 384;
        bf16 v = (bf16)0.f;
        if (col < 24) {
            int gc = br * 96 + hd * 24 + col;
            if (seg == 0)      v = (bf16)Wq[k * 192 + gc];
            else if (seg == 1) v = (bf16)Wkv[k * 384 + gc];
            else               v = (bf16)Wkv[k * 384 + 192 + gc];
        }
        Wt2[(size_t)id * 192 + k] = v;
    } else {
        int col = id - 768;
        Wpt[(size_t)col * 192 + k] = (bf16)Wp[k * 192 + col];
    }
}

// ---------------- fused QKV-GEMM + windowed attention, wave-local ------------
// grid (4096, 2). 4 waves = 4 heads, each wave fully owns its head:
// QKV (6 padded 16-col tiles) -> private LDS -> QK^T -> DPP softmax -> PV.
// Only 3 barriers: B1 (X staged), B1.5 (xs alias release), B4 (ob ready).
// LDS ledger:
//   [0, 30720):      4 x 7680 per-wave {Q[32][40], K[32][40], VT[32][40]}
//                    xs[32][200] (12800 B) aliases wave0 all + wave1 Q,K:
//                    xs reads end at B1.5; Q/K/VT writes start after B1.5.
//                    PL[32][40] aliases Q per-wave (same-wave dataflow order:
//                    PL writes depend on QK MFMA which depends on Q reads).
//   [30720, 37376):  ob[32][104] output staging (B4-protected).
__global__ __launch_bounds__(256, 4) void kfused(const float* __restrict__ X,
                                                 const bf16* __restrict__ Wt2,
                                                 bf16* __restrict__ Out) {
    const int branch = blockIdx.y;
    const int bw = blockIdx.x;
    const int img = bw >> 9;
    const int widx = bw & 511;
    const int wh = branch ? 8 : 4, ww = branch ? 4 : 8;
    const int lww = branch ? 2 : 3;           // log2(ww)
    const int lnv = branch ? 5 : 4;           // log2(128/ww)
    const int sh = wh >> 1, sw = ww >> 1;
    const int wa = widx >> lnv;
    const int wb = widx & ((128 >> lww) - 1);

    __shared__ __align__(16) char smem[37376];
    __shared__ int pix[32];
    __shared__ int rid[32];

    const int tid = threadIdx.x;
    const int hd = tid >> 6;
    const int l = tid & 63, li = l & 15, lk = l >> 4;

    bf16 (*xs)[200] = (bf16(*)[200])smem;                       // pre-B1.5
    char* wbase = smem + hd * 7680;
    bf16 (*Q)[40]  = (bf16(*)[40])wbase;                        // post-B1.5
    bf16 (*K)[40]  = (bf16(*)[40])(wbase + 2560);
    bf16 (*VT)[40] = (bf16(*)[40])(wbase + 5120);
    bf16 (*PL)[40] = Q;                                         // aliases Q
    bf16 (*ob)[104] = (bf16(*)[104])(smem + 30720);

    if (tid < 32) {
        int ih = tid >> lww, iw = tid & (ww - 1);
        int hh = wa * wh + ih, wp = wb * ww + iw;          // rolled coords
        int hreg = (hh >= 128 - wh) + (hh >= 128 - sh);
        int wreg = (wp >= 128 - ww) + (wp >= 128 - sw);
        rid[tid] = hreg * 3 + wreg;
        int srh = (hh + sh) & 127, srw = (wp + sw) & 127;  // source pixel
        pix[tid] = img * 16384 + srh * 128 + srw;
    }

    // ---- stage X rows: 32 x 192 fp32 -> bf16; inline rolled-pixel address ----
    {
        int row = tid / 48, rem = tid % 48;
#pragma unroll
        for (int i = 0; i < 6; ++i) {
            int c4 = rem * 4;
            int ih = row >> lww, iw = row & (ww - 1);
            int hh = wa * wh + ih, wp = wb * ww + iw;
            int srh = (hh + sh) & 127, srw = (wp + sw) & 127;
            f32x4 f = *(const f32x4*)(X + (size_t)(img * 16384 + srh * 128 + srw) * 192 + c4);
            bf16x4 h;
#pragma unroll
            for (int e = 0; e < 4; ++e) h[e] = (bf16)f[e];
            *(bf16x4*)&xs[row][c4] = h;
            row += 5; rem += 16;
            if (rem >= 48) { rem -= 48; ++row; }
        }
    }
    __syncthreads();   // B1: xs + pix + rid ready

    // ---- preload X fragments (all waves read the same xs) ----
    bf16x8 xf[2][6];
#pragma unroll
    for (int mt = 0; mt < 2; ++mt)
#pragma unroll
        for (int ks = 0; ks < 6; ++ks)
            xf[mt][ks] = *(const bf16x8*)&xs[mt * 16 + li][ks * 32 + lk * 8];

#define LOADW(dst, seg_, t_) {                                                      \
        const bf16* wr = Wt2 + ((size_t)((branch * 3 + (seg_)) * 4 + hd) * 32       \
                                + (t_) * 16 + li) * 192 + lk * 8;                   \
        _Pragma("unroll")                                                           \
        for (int ks = 0; ks < 6; ++ks) dst[ks] = *(const bf16x8*)(wr + ks * 32);    \
    }

    bf16x8 cur[6], nxt[6];
    LOADW(cur, 0, 0);      // first W-tile loads fly across the barrier
    __syncthreads();       // B1.5: all xf reads done -> Q/K/VT may overwrite xs

    // ---- wave-local QKV: 6 tiles (q0,q1,k0,k1,v0,v1), depth-2 prefetch ----
#pragma unroll
    for (int j = 0; j < 6; ++j) {
        if (j < 5) {
            const int jn = j + 1;
            LOADW(nxt, jn >> 1, jn & 1);
        }
        f32x4 a0 = zero4(), a1 = zero4();
#pragma unroll
        for (int ks = 0; ks < 6; ++ks) {
            a0 = mfma16(cur[ks], xf[0][ks], a0);
            a1 = mfma16(cur[ks], xf[1][ks], a1);
        }
        const int seg = j >> 1, t = j & 1;
        // D: head-local col = t*16 + lk*4 + r (regs), token = li / 16+li (lanes)
        if (seg < 2) {
            bf16 (*dst)[40] = seg ? K : Q;
            bf16x4 p0, p1;
#pragma unroll
            for (int r = 0; r < 4; ++r) { p0[r] = (bf16)a0[r]; p1[r] = (bf16)a1[r]; }
            *(bf16x4*)&dst[li][t * 16 + lk * 4] = p0;
            *(bf16x4*)&dst[16 + li][t * 16 + lk * 4] = p1;
        } else {
#pragma unroll
            for (int r = 0; r < 4; ++r) {
                VT[t * 16 + lk * 4 + r][li] = (bf16)a0[r];
                VT[t * 16 + lk * 4 + r][16 + li] = (bf16)a1[r];
            }
        }
#pragma unroll
        for (int ks = 0; ks < 6; ++ks) cur[ks] = nxt[ks];
    }

    // ---- QK^T (K=32, cols 24..31 are exact zeros from the weight pad) ----
    bf16x8 aq[2], bk[2];
#pragma unroll
    for (int t = 0; t < 2; ++t) {
        aq[t] = *(const bf16x8*)&Q[t * 16 + li][lk * 8];
        bk[t] = *(const bf16x8*)&K[t * 16 + li][lk * 8];
    }
    f32x4 s[2][2];
#pragma unroll
    for (int it = 0; it < 2; ++it)
#pragma unroll
        for (int jt = 0; jt < 2; ++jt) s[it][jt] = mfma16(aq[it], bk[jt], zero4());

    // ---- softmax (DPP rotate-reduce; PL aliases Q, same-wave dataflow order) ----
    const float scale = 0.2041241452319315f;  // 24^-0.5
    const int r0 = lk * 4;
    const int rj0 = rid[li], rj1 = rid[16 + li];
#pragma unroll
    for (int it = 0; it < 2; ++it) {
#pragma unroll
        for (int r = 0; r < 4; ++r) {
            int i = it * 16 + r0 + r;
            int ri = rid[i];
            float v0 = s[it][0][r] * scale + ((ri != rj0) ? -100.f : 0.f);
            float v1 = s[it][1][r] * scale + ((ri != rj1) ? -100.f : 0.f);
            float m = rowmax16(fmaxf(v0, v1));
            float e0 = __expf(v0 - m), e1 = __expf(v1 - m);
            float sm = rowsum16(e0 + e1);
            float inv = 1.f / sm;
            PL[i][li] = (bf16)(e0 * inv);
            PL[i][16 + li] = (bf16)(e1 * inv);
        }
    }

    // ---- O = P @ V (wave-local) ----
    bf16x8 ap[2], bv[2];
#pragma unroll
    for (int it = 0; it < 2; ++it)
        ap[it] = *(const bf16x8*)&PL[it * 16 + li][lk * 8];
#pragma unroll
    for (int ct = 0; ct < 2; ++ct)
        bv[ct] = *(const bf16x8*)&VT[ct * 16 + li][lk * 8];
    f32x4 o[2][2];
#pragma unroll
    for (int it = 0; it < 2; ++it)
#pragma unroll
        for (int ct = 0; ct < 2; ++ct) o[it][ct] = mfma16(ap[it], bv[ct], zero4());

    // stage O (cols 24..31 are zero/garbage -> guarded), coalesced writeback
#pragma unroll
    for (int it = 0; it < 2; ++it)
#pragma unroll
        for (int ct = 0; ct < 2; ++ct) {
            int col = ct * 16 + li;
            if (col < 24) {
#pragma unroll
                for (int r = 0; r < 4; ++r)
                    ob[it * 16 + r0 + r][hd * 24 + col] = (bf16)o[it][ct][r];
            }
        }
    __syncthreads();   // B4: ob complete across all heads
    for (int c = tid; c < 384; c += 256) {    // 32 tokens x 12 chunks of 8
        int row = c / 12, ch = c % 12;
        *(bf16x8*)(Out + (size_t)pix[row] * 192 + branch * 96 + ch * 8) =
            *(const bf16x8*)&ob[row][ch * 8];
    }
#undef LOADW
}

// ---------------- output projection: fp32 out = Ab @ Wproj + bias --------------
#define BSTR 200
__global__ __launch_bounds__(256, 4) void kproj(const bf16* __restrict__ Ab,
                                                const bf16* __restrict__ Wpt,
                                                const float* __restrict__ bias,
                                                float* __restrict__ Out) {
    __shared__ __align__(16) bf16 Bs[96][BSTR];
    const int lid = blockIdx.x;
    const int xcd = lid & 7, s = lid >> 3;       // s: 0..255
    const int mg = xcd * 128 + s / 2;            // 0..1023
    const int nb = s & 1;
    const int tid = threadIdx.x;
    const int w = tid >> 6, l = tid & 63, li = l & 15, lk = l >> 4;
    const int rb = mg * 128 + w * 32;
    const int cb = nb * 96;

    // A-loads first (12 dwordx4 in flight)
    bf16x8 a[2][6];
#pragma unroll
    for (int it = 0; it < 2; ++it)
#pragma unroll
        for (int ks = 0; ks < 6; ++ks)
            a[it][ks] = *(const bf16x8*)(Ab + (size_t)(rb + it * 16 + li) * 192 + ks * 32 + lk * 8);

#pragma unroll
    for (int i = 0; i < 9; ++i) {
        int c = i * 256 + tid;
        int r = c / 24, col = (c % 24) * 8;
        *(bf16x8*)&Bs[r][col] = *(const bf16x8*)(Wpt + (size_t)(cb + r) * 192 + col);
    }
    __syncthreads();

    f32x4 acc[2][6];
#pragma unroll
    for (int it = 0; it < 2; ++it)
#pragma unroll
        for (int nt = 0; nt < 6; ++nt) acc[it][nt] = zero4();

#pragma unroll
    for (int nt = 0; nt < 6; ++nt) {
#pragma unroll
        for (int ks = 0; ks < 6; ++ks) {
            bf16x8 b = *(const bf16x8*)&Bs[nt * 16 + li][ks * 32 + lk * 8];
            acc[0][nt] = mfma16(b, a[0][ks], acc[0][nt]);
            acc[1][nt] = mfma16(b, a[1][ks], acc[1][nt]);
        }
    }

    // D[n][m]: row = rb+it*16+li, cols = cb+nt*16+lk*4+(0..3) -> f32x4 stores
#pragma unroll
    for (int nt = 0; nt < 6; ++nt) {
        f32x4 bv4 = *(const f32x4*)(bias + cb + nt * 16 + lk * 4);
#pragma unroll
        for (int it = 0; it < 2; ++it) {
            f32x4 ov = acc[it][nt];
#pragma unroll
            for (int r = 0; r < 4; ++r) ov[r] += bv4[r];
            *(f32x4*)(Out + (size_t)(rb + it * 16 + li) * 192 + cb + nt * 16 + lk * 4) = ov;
        }
    }
}

extern "C" void kernel_launch(void* const* d_in, const int* in_sizes, int n_in,
                              void* d_out, int out_size, void* d_ws, size_t ws_size,
                              hipStream_t stream) {
    const float* x    = (const float*)d_in[0];
    const float* Wq   = (const float*)d_in[1];
    const float* Wkv  = (const float*)d_in[2];
    const float* Wp   = (const float*)d_in[3];
    const float* bias = (const float*)d_in[4];
    float* out = (float*)d_out;

    bf16* Ab  = (bf16*)d_ws;                       // 131072 x 192 bf16 = 48 MiB
    bf16* Wt2 = Ab + (size_t)MROWS * 192;          // 768 x 192 (head-padded)
    bf16* Wpt = Wt2 + 768 * 192;                   // 192 x 192

    hipLaunchKernelGGL(kw_transpose, dim3(960), dim3(192), 0, stream, Wq, Wkv, Wp, Wt2, Wpt);
    hipLaunchKernelGGL(kfused, dim3(4096, 2), dim3(256), 0, stream, x, Wt2, Ab);
    hipLaunchKernelGGL(kproj, dim3(2048), dim3(256), 0, stream, Ab, Wpt, bias, out);
}